// Round 1
// baseline (254.644 us; speedup 1.0000x reference)
//
#include <hip/hip_runtime.h>
#include <hip/hip_bf16.h>

constexpr int B_ = 8;
constexpr int N_ = 2048;
constexpr int FIN = 128;
constexpr int FOUT = 64;
constexpr float ALPHA_ = 0.2f;
constexpr float NEG_INF_ = -9000000000000000.0f;

constexpr int TILE_I = 32;   // attention rows per block
constexpr int CHUNK = 128;   // j-columns per LDS chunk
constexpr int NT = 256;      // threads per block (4 waves)

// Kernel 1: Wh = h @ W  (one 64-thread wave per (b,n) row), plus
// si = Wh . a1, sj = Wh . a2 via wave reduction.
__global__ __launch_bounds__(64) void gat_wh_kernel(
    const float* __restrict__ h, const float* __restrict__ W,
    const float* __restrict__ a, float* __restrict__ Wh,
    float* __restrict__ si, float* __restrict__ sj) {
  const int row = blockIdx.x;  // b*N + n
  const int f = threadIdx.x;   // 0..63
  __shared__ float hrow[FIN];
  hrow[f] = h[(size_t)row * FIN + f];
  hrow[f + 64] = h[(size_t)row * FIN + f + 64];
  __syncthreads();
  float acc = 0.f;
#pragma unroll
  for (int k = 0; k < FIN; ++k) acc = fmaf(hrow[k], W[k * FOUT + f], acc);
  Wh[(size_t)row * FOUT + f] = acc;
  float p1 = acc * a[f];
  float p2 = acc * a[FOUT + f];
#pragma unroll
  for (int off = 32; off; off >>= 1) {
    p1 += __shfl_down(p1, off);
    p2 += __shfl_down(p2, off);
  }
  if (f == 0) {
    si[row] = p1;
    sj[row] = p2;
  }
}

// Kernel 2: fused masked-softmax + attention write + h' = att @ Wh + elu.
// Block handles TILE_I rows of one batch. grid = B * (N/TILE_I) = 512.
__global__ __launch_bounds__(NT) void gat_attn_kernel(
    const int* __restrict__ adj, const float* __restrict__ Wh,
    const float* __restrict__ si, const float* __restrict__ sj,
    float* __restrict__ att_out, float* __restrict__ h_out) {
  const int nblk = N_ / TILE_I;
  const int b = blockIdx.x / nblk;
  const int i0 = (blockIdx.x % nblk) * TILE_I;
  const int tid = threadIdx.x;
  const int lane = tid & 63;
  const int wv = tid >> 6;

  __shared__ float s_m[TILE_I];
  __shared__ float s_r[TILE_I];
  __shared__ float s_si[TILE_I];
  __shared__ float att_tile[TILE_I][CHUNK + 4];  // +4 pad: conflict-free bcast reads
  __shared__ float wh_tile[CHUNK][FOUT];

  const float* __restrict__ sjb = sj + b * N_;

  if (tid < TILE_I) s_si[tid] = si[b * N_ + i0 + tid];

  // ---- Phase 1: per-row online softmax stats (max m, sum s). ----
  // Wave wv owns rows [wv*8, wv*8+8); 64 lanes stride the 2048 columns.
#pragma unroll
  for (int rr = 0; rr < TILE_I / 4; ++rr) {
    const int r = wv * (TILE_I / 4) + rr;
    const int* __restrict__ adjrow = adj + (size_t)(i0 + r) * N_;
    const float siv = si[b * N_ + i0 + r];
    float m = -3.0e38f;
    float s = 0.f;
    for (int j = lane; j < N_; j += 64) {
      float e0 = siv + sjb[j];
      float v = e0 > 0.f ? e0 : ALPHA_ * e0;
      if (adjrow[j] <= 0) v = NEG_INF_;  // finite, matches reference semantics
      if (v <= m) {
        s += __expf(v - m);
      } else {
        s = s * __expf(m - v) + 1.f;  // rare rescale branch
        m = v;
      }
    }
    // combine (m,s) across the 64-lane wave
#pragma unroll
    for (int off = 1; off < 64; off <<= 1) {
      float m2 = __shfl_xor(m, off);
      float s2 = __shfl_xor(s, off);
      float mn = fmaxf(m, m2);
      s = s * __expf(m - mn) + s2 * __expf(m2 - mn);
      m = mn;
    }
    if (lane == 0) {
      s_m[r] = m;
      s_r[r] = 1.f / s;
    }
  }
  __syncthreads();

  // ---- Phase 2: chunked att compute+write, fused h' accumulation. ----
  // Thread owns (row r2, features fg*8 .. fg*8+7) -> no cross-thread reduce.
  const int r2 = tid >> 3;
  const int fg = tid & 7;
  float acc[8];
#pragma unroll
  for (int k = 0; k < 8; ++k) acc[k] = 0.f;

  for (int j0 = 0; j0 < N_; j0 += CHUNK) {
    // stage Wh chunk (CHUNK x FOUT f32) into LDS (coalesced, conflict-free)
    for (int idx = tid; idx < CHUNK * FOUT; idx += NT) {
      int jj = idx >> 6;
      int f = idx & 63;
      wh_tile[jj][f] = Wh[(size_t)(b * N_ + j0 + jj) * FOUT + f];
    }
    // compute att values for the tile, write to LDS + global (coalesced)
    for (int idx = tid; idx < TILE_I * CHUNK; idx += NT) {
      int r = idx >> 7;
      int jj = idx & (CHUNK - 1);
      int j = j0 + jj;
      float e0 = s_si[r] + sjb[j];
      float v = e0 > 0.f ? e0 : ALPHA_ * e0;
      if (adj[(size_t)(i0 + r) * N_ + j] <= 0) v = NEG_INF_;
      float av = __expf(v - s_m[r]) * s_r[r];  // exactly 0 for masked (underflow)
      att_tile[r][jj] = av;
      att_out[(size_t)(b * N_ + i0 + r) * N_ + j] = av;
    }
    __syncthreads();

    // accumulate h'[r2][fg*8+k] over this chunk
#pragma unroll 2
    for (int jj = 0; jj < CHUNK; jj += 4) {
      float4 av4 = *(const float4*)&att_tile[r2][jj];
#pragma unroll
      for (int q = 0; q < 4; ++q) {
        float av = (q == 0) ? av4.x : (q == 1) ? av4.y : (q == 2) ? av4.z : av4.w;
        float4 w0 = *(const float4*)&wh_tile[jj + q][fg * 8];
        float4 w1 = *(const float4*)&wh_tile[jj + q][fg * 8 + 4];
        acc[0] = fmaf(av, w0.x, acc[0]);
        acc[1] = fmaf(av, w0.y, acc[1]);
        acc[2] = fmaf(av, w0.z, acc[2]);
        acc[3] = fmaf(av, w0.w, acc[3]);
        acc[4] = fmaf(av, w1.x, acc[4]);
        acc[5] = fmaf(av, w1.y, acc[5]);
        acc[6] = fmaf(av, w1.z, acc[6]);
        acc[7] = fmaf(av, w1.w, acc[7]);
      }
    }
    __syncthreads();
  }

  // ---- Epilogue: elu + coalesced store ----
  float o[8];
#pragma unroll
  for (int k = 0; k < 8; ++k) {
    float x = acc[k];
    o[k] = x > 0.f ? x : __expf(x) - 1.f;
  }
  float* dst = h_out + (size_t)(b * N_ + i0 + r2) * FOUT + fg * 8;
  *(float4*)dst = make_float4(o[0], o[1], o[2], o[3]);
  *(float4*)(dst + 4) = make_float4(o[4], o[5], o[6], o[7]);
}

extern "C" void kernel_launch(void* const* d_in, const int* in_sizes, int n_in,
                              void* d_out, int out_size, void* d_ws, size_t ws_size,
                              hipStream_t stream) {
  const float* h = (const float*)d_in[0];
  const int* adj = (const int*)d_in[1];
  const float* W = (const float*)d_in[2];
  const float* a = (const float*)d_in[3];

  float* out = (float*)d_out;
  float* h_out = out;                              // B*N*FOUT (elu(h'))
  float* att_out = out + (size_t)B_ * N_ * FOUT;   // B*N*N (attention)

  float* Wh = (float*)d_ws;                        // B*N*FOUT
  float* si = Wh + (size_t)B_ * N_ * FOUT;         // B*N
  float* sj = si + (size_t)B_ * N_;                // B*N

  gat_wh_kernel<<<B_ * N_, 64, 0, stream>>>(h, W, a, Wh, si, sj);
  gat_attn_kernel<<<B_ * (N_ / TILE_I), NT, 0, stream>>>(adj, Wh, si, sj,
                                                         att_out, h_out);
}

// Round 2
// 80.141 us; speedup vs baseline: 3.1775x; 3.1775x over previous
//
#include <hip/hip_runtime.h>
#include <hip/hip_bf16.h>
#include <string.h>

constexpr int B_ = 8;
constexpr int N_ = 2048;
constexpr int FIN = 128;
constexpr int FOUT = 64;
constexpr float ALPHA_ = 0.2f;
constexpr float NEG_INF_ = -9000000000000000.0f;

typedef __attribute__((ext_vector_type(8))) short bf16x8;
typedef __attribute__((ext_vector_type(4))) float f32x4;

static __device__ __forceinline__ unsigned short f2bf(float x) {
  unsigned int u = __float_as_uint(x);
  unsigned int r = u + 0x7fffu + ((u >> 16) & 1u);
  return (unsigned short)(r >> 16);
}

// ---------------- Kernel 1: Wh^T (bf16) + si/sj (f32, exact) ----------------
// 4 waves/block, 8 rows per wave. grid = B*N/32 = 512.
__global__ __launch_bounds__(256) void k_wh(
    const float* __restrict__ h, const float* __restrict__ W,
    const float* __restrict__ a, unsigned short* __restrict__ WhT,
    float* __restrict__ si, float* __restrict__ sj) {
  const int lane = threadIdx.x & 63;
  const int wv = threadIdx.x >> 6;
  const int grow0 = blockIdx.x * 32 + wv * 8;  // b*N + n, 8 rows
  const int f = lane;
  float acc[8] = {0.f, 0.f, 0.f, 0.f, 0.f, 0.f, 0.f, 0.f};
  const float* hp = h + (size_t)grow0 * FIN;
#pragma unroll 4
  for (int k = 0; k < FIN; k += 4) {
    float w0 = W[k * FOUT + f];
    float w1 = W[(k + 1) * FOUT + f];
    float w2 = W[(k + 2) * FOUT + f];
    float w3 = W[(k + 3) * FOUT + f];
#pragma unroll
    for (int r = 0; r < 8; ++r) {
      float4 hv = *(const float4*)(hp + r * FIN + k);
      acc[r] = fmaf(hv.x, w0, acc[r]);
      acc[r] = fmaf(hv.y, w1, acc[r]);
      acc[r] = fmaf(hv.z, w2, acc[r]);
      acc[r] = fmaf(hv.w, w3, acc[r]);
    }
  }
  const float a1 = a[f], a2 = a[FOUT + f];
#pragma unroll
  for (int r = 0; r < 8; ++r) {
    float p1 = acc[r] * a1;
    float p2 = acc[r] * a2;
#pragma unroll
    for (int off = 32; off; off >>= 1) {
      p1 += __shfl_xor(p1, off);
      p2 += __shfl_xor(p2, off);
    }
    if (lane == 0) {
      si[grow0 + r] = p1;
      sj[grow0 + r] = p2;
    }
  }
  // WhT[b][f][n0..n0+7] <- acc[0..7]  (16B store per lane)
  const int b = grow0 >> 11;
  const int n0 = grow0 & (N_ - 1);
  __align__(16) unsigned short u[8];
#pragma unroll
  for (int r = 0; r < 8; ++r) u[r] = f2bf(acc[r]);
  *(bf16x8*)&WhT[(((size_t)(b * FOUT + f)) << 11) + n0] = *(const bf16x8*)u;
}

// ---------------- Kernel 2: adj -> bitmasks ----------------
// wave per row, 4 rows/block, grid = N/4 = 512.
// mask_rm[r][it] u64: bit l = adj[r][it*64+l] > 0   (row-major bits)
// mask_t [r][l]  u32: bit it = adj[r][it*64+l] > 0  (lane-major, for k_stats)
__global__ __launch_bounds__(256) void k_pack(
    const int* __restrict__ adj, unsigned long long* __restrict__ mask_rm,
    unsigned int* __restrict__ mask_t) {
  const int lane = threadIdx.x & 63;
  const int wv = threadIdx.x >> 6;
  const int r = blockIdx.x * 4 + wv;
  const int* row = adj + (size_t)r * N_;
  unsigned int wacc = 0;
#pragma unroll
  for (int it = 0; it < 32; ++it) {
    int v = row[it * 64 + lane];
    unsigned long long bm = __ballot(v > 0);
    if (lane == 0) mask_rm[r * 32 + it] = bm;
    wacc |= ((unsigned int)(v > 0)) << it;
  }
  mask_t[r * 64 + lane] = wacc;
}

// ---------------- Kernel 3: per-row softmax stats ----------------
// m_row = lrelu(si + max_{allowed j} sj)  (lrelu monotonic), r_row = 1/sum.
// wave per row, 4 rows/block, grid = B*N/4 = 4096.
__global__ __launch_bounds__(256) void k_stats(
    const unsigned int* __restrict__ mask_t, const float* __restrict__ si,
    const float* __restrict__ sj, float* __restrict__ mrow,
    float* __restrict__ rrow) {
  const int lane = threadIdx.x & 63;
  const int wv = threadIdx.x >> 6;
  const int row = blockIdx.x * 4 + wv;  // b*N + i
  const int b = row >> 11;
  const int i = row & (N_ - 1);
  const unsigned int w32 = mask_t[i * 64 + lane];
  const float* sjb = sj + ((size_t)b << 11);
  float sjv[32];
  float M = -3.0e38f;
#pragma unroll
  for (int it = 0; it < 32; ++it) {
    sjv[it] = sjb[it * 64 + lane];
    if ((w32 >> it) & 1u) M = fmaxf(M, sjv[it]);
  }
#pragma unroll
  for (int off = 32; off; off >>= 1) M = fmaxf(M, __shfl_xor(M, off));
  const float siv = si[row];
  const float e0 = siv + M;
  const float m = e0 > 0.f ? e0 : ALPHA_ * e0;
  float s = 0.f;
#pragma unroll
  for (int it = 0; it < 32; ++it) {
    float e = siv + sjv[it];
    float v = e > 0.f ? e : ALPHA_ * e;
    float p = __expf(v - m);
    s += ((w32 >> it) & 1u) ? p : 0.f;
  }
#pragma unroll
  for (int off = 32; off; off >>= 1) s += __shfl_xor(s, off);
  if (lane == 0) {
    mrow[row] = m;
    rrow[row] = 1.f / s;
  }
}

// ---------------- Kernel 4: att write + h' = att @ Wh via MFMA ----------------
// 32 rows/block, 8 waves, j-chunks of 128. grid = B*N/32 = 512 (2 blocks/CU).
constexpr int TI = 32;
constexpr int CH = 128;

__global__ __launch_bounds__(512) void k_main(
    const unsigned short* __restrict__ WhT,
    const unsigned long long* __restrict__ mask_rm,
    const float* __restrict__ si, const float* __restrict__ sjg,
    const float* __restrict__ mrow, const float* __restrict__ rrow,
    float* __restrict__ att_out, float* __restrict__ h_out) {
  __shared__ __align__(16) unsigned short A_lds[TI * CH];    // 8 KB, swizzled
  __shared__ __align__(16) unsigned short Bt_lds[FOUT * CH]; // 16 KB, swizzled
  __shared__ float s_sj[N_];                                 // 8 KB
  __shared__ float s_si[TI], s_m[TI], s_r[TI];

  // XCD-aware swizzle: 512 blocks, XCD x <-> batch x (WhT/sj/mask L2-resident)
  const int bid = blockIdx.x;
  const int swz = (bid & 7) * 64 + (bid >> 3);
  const int b = swz >> 6;
  const int i0 = (swz & 63) * TI;

  const int tid = threadIdx.x;
  const int lane = tid & 63;
  const int wv = tid >> 6;
  const int rt = wv >> 2;  // 0..1 : 16-row tile
  const int ct = wv & 3;   // 0..3 : 16-col tile

  const unsigned char* maskb = (const unsigned char*)mask_rm;
  char* Ab = (char*)A_lds;
  char* Bb = (char*)Bt_lds;

  for (int x = tid; x < N_; x += 512) s_sj[x] = sjg[(b << 11) + x];
  if (tid < TI) {
    s_si[tid] = si[(b << 11) + i0 + tid];
    s_m[tid] = mrow[(b << 11) + i0 + tid];
    s_r[tid] = rrow[(b << 11) + i0 + tid];
  }
  __syncthreads();

  f32x4 acc = {0.f, 0.f, 0.f, 0.f};

  const int r = tid >> 4;  // 0..31: att row this thread computes
  const int q = tid & 15;  // 8-col unit within chunk

  for (int j0 = 0; j0 < N_; j0 += CH) {
    // ---- stage B = WhT[b][f][j0..j0+127] into swizzled LDS ----
#pragma unroll
    for (int p = 0; p < 2; ++p) {
      const int fr = (tid >> 4) + p * 32;  // 0..63
      bf16x8 v = *(const bf16x8*)&WhT[(((size_t)(b * FOUT + fr)) << 11) + j0 + q * 8];
      *(bf16x8*)(Bb + ((fr * 256 + q * 16) ^ ((fr & 7) << 4))) = v;
    }
    // ---- compute 8 att values, write f32 global + bf16 swizzled LDS ----
    {
      const int jb = j0 + q * 8;
      const unsigned int mbits = maskb[(i0 + r) * 256 + (jb >> 3)];
      const float sir = s_si[r], mr = s_m[r], rr = s_r[r];
      const float4 sj0 = *(const float4*)&s_sj[jb];
      const float4 sj1 = *(const float4*)&s_sj[jb + 4];
      const float sjl[8] = {sj0.x, sj0.y, sj0.z, sj0.w, sj1.x, sj1.y, sj1.z, sj1.w};
      float av[8];
#pragma unroll
      for (int e = 0; e < 8; ++e) {
        float ev = sir + sjl[e];
        float v = ev > 0.f ? ev : ALPHA_ * ev;
        float p = __expf(v - mr) * rr;
        av[e] = ((mbits >> e) & 1u) ? p : 0.f;
      }
      float* ao = att_out + (((size_t)((b << 11) + i0 + r)) << 11) + jb;
      *(float4*)ao = make_float4(av[0], av[1], av[2], av[3]);
      *(float4*)(ao + 4) = make_float4(av[4], av[5], av[6], av[7]);
      __align__(16) unsigned short u[8];
#pragma unroll
      for (int e = 0; e < 8; ++e) u[e] = f2bf(av[e]);
      *(bf16x8*)(Ab + ((r * 256 + q * 16) ^ ((r & 7) << 4))) = *(const bf16x8*)u;
    }
    __syncthreads();
    // ---- MFMA: acc += A(16x32) * B(32x16) over the 4 k-steps of this chunk ----
    {
      const int arow = rt * 16 + (lane & 15);
      const int brow = ct * 16 + (lane & 15);
      const int kb = (lane >> 4) * 16;  // byte offset of this lane's 8-elem k-group
      const int axor = (arow & 7) << 4;
      const int bxor = (brow & 7) << 4;
#pragma unroll
      for (int ks = 0; ks < 4; ++ks) {
        bf16x8 af = *(const bf16x8*)(Ab + ((arow * 256 + ks * 64 + kb) ^ axor));
        bf16x8 bv = *(const bf16x8*)(Bb + ((brow * 256 + ks * 64 + kb) ^ bxor));
        acc = __builtin_amdgcn_mfma_f32_16x16x32_bf16(af, bv, acc, 0, 0, 0);
      }
    }
    __syncthreads();
  }

  // ---- epilogue: elu + store (C/D layout: col=lane&15, row=(lane>>4)*4+reg) ----
  const int colb = ct * 16 + (lane & 15);
  const int rowb = i0 + rt * 16 + ((lane >> 4) << 2);
#pragma unroll
  for (int qq = 0; qq < 4; ++qq) {
    float x = acc[qq];
    float o = x > 0.f ? x : __expf(x) - 1.f;
    h_out[(((size_t)((b << 11) + rowb + qq)) << 6) + colb] = o;
  }
}

extern "C" void kernel_launch(void* const* d_in, const int* in_sizes, int n_in,
                              void* d_out, int out_size, void* d_ws, size_t ws_size,
                              hipStream_t stream) {
  const float* h = (const float*)d_in[0];
  const int* adj = (const int*)d_in[1];
  const float* W = (const float*)d_in[2];
  const float* a = (const float*)d_in[3];

  float* out = (float*)d_out;
  float* h_out = out;                             // B*N*FOUT
  float* att_out = out + (size_t)B_ * N_ * FOUT;  // B*N*N

  // workspace layout (~3.3 MB)
  unsigned short* WhT = (unsigned short*)d_ws;                       // 2 MB
  float* si = (float*)((char*)d_ws + (size_t)2 * 1024 * 1024);       // 64 KB
  float* sj = si + B_ * N_;                                          // 64 KB
  float* mrow = sj + B_ * N_;                                        // 64 KB
  float* rrow = mrow + B_ * N_;                                      // 64 KB
  unsigned long long* mask_rm = (unsigned long long*)(rrow + B_ * N_);  // 512 KB
  unsigned int* mask_t = (unsigned int*)((char*)mask_rm + (size_t)N_ * 32 * 8);  // 512 KB

  k_wh<<<B_ * N_ / 32, 256, 0, stream>>>(h, W, a, WhT, si, sj);
  k_pack<<<N_ / 4, 256, 0, stream>>>(adj, mask_rm, mask_t);
  k_stats<<<B_ * N_ / 4, 256, 0, stream>>>(mask_t, si, sj, mrow, rrow);
  k_main<<<B_ * N_ / TI, 512, 0, stream>>>(WhT, mask_rm, si, sj, mrow, rrow,
                                           att_out, h_out);
}